// Round 4
// baseline (43952.872 us; speedup 1.0000x reference)
//
#include <hip/hip_runtime.h>

#define TT   512
#define NBOX 30
#define HDIM 512
#define M1 (TT*31)     // 15872
#define N1 HDIM        // 512
#define K1 4096
#define M2 (TT*NBOX)   // 15360
#define N2 (3*HDIM)    // 1536
#define K2 (2*HDIM)    // 1024
#define NWG 256

// dynamic LDS layout (floats):
//   Hs0  [30][516]   15480  @0      staged h0_n(t)
//   Hs1  [30][516]   15480  @15480  staged h1_n(t-1)
//   Wp   [12][516]    6192  @30960  Whh0/Wih1 col-triples (WG255: coord overlay)
//   gi_s [30][6]       180  @37152
//   Z0s  [30][6]       180  @37332  (aliased: s0W[30][4] during staging/softmax)
//   Z1s  [30][6]       180  @37512  (aliased: s1W[30][4])
//   sm0  [32]           32  @37692
//   sm1  [32]           32  @37724
//   redF [72]           72  @37756
//   hcs  [960]         960  @37828  staged hc(t-1) for classifier
#define DYN_FLOATS 38788
#define DYN_BYTES  (DYN_FLOATS * 4)

__device__ __forceinline__ float4 ld4(const float* p) { return *(const float4*)p; }
__device__ __forceinline__ float dot4(float4 a, float4 b) { return a.x*b.x + a.y*b.y + a.z*b.z + a.w*b.w; }
__device__ __forceinline__ float sigf(float x) { return 1.f / (1.f + __expf(-x)); }
__device__ __forceinline__ float thf(float x)  { return 1.f - 2.f / (1.f + __expf(2.f*x)); }

// --- coherent (L2-bypassing, LLC-visible) accessors: no fences anywhere ----
__device__ __forceinline__ float ldg_c(const float* p) {
    return __hip_atomic_load((float*)p, __ATOMIC_RELAXED, __HIP_MEMORY_SCOPE_AGENT);
}
__device__ __forceinline__ void stg_c(float* p, float v) {
    __hip_atomic_store(p, v, __ATOMIC_RELAXED, __HIP_MEMORY_SCOPE_AGENT);
}
__device__ __forceinline__ float2 ldg_c2(const float* p) {
    unsigned long long u = __hip_atomic_load((unsigned long long*)p, __ATOMIC_RELAXED, __HIP_MEMORY_SCOPE_AGENT);
    float2 r;
    r.x = __uint_as_float((unsigned)u);
    r.y = __uint_as_float((unsigned)(u >> 32));
    return r;
}
__device__ __forceinline__ void stg_c2(float* p, float a, float b) {
    unsigned long long u = ((unsigned long long)__float_as_uint(b) << 32) | (unsigned long long)__float_as_uint(a);
    __hip_atomic_store((unsigned long long*)p, u, __ATOMIC_RELAXED, __HIP_MEMORY_SCOPE_AGENT);
}

// ---------------------------------------------------------------------------
// GEMM 1: xv = relu(flow @ W_phi + b_phi)   (unchanged)
// ---------------------------------------------------------------------------
__global__ __launch_bounds__(256) void gemm_phi(const float* __restrict__ A,
                                                const float* __restrict__ B,
                                                const float* __restrict__ bias,
                                                float* __restrict__ C) {
    __shared__ float As[16][68];
    __shared__ float Bs[16][68];
    const int tid = threadIdx.x;
    const int m0 = blockIdx.x * 64;
    const int n0 = blockIdx.y * 64;
    const int am = tid >> 2, ak = (tid & 3) << 2;
    const int bk = tid >> 4, bn = (tid & 15) << 2;
    const int ty = tid >> 4, tx = tid & 15;
    float acc[4][4] = {};
    for (int k0 = 0; k0 < K1; k0 += 16) {
        const float4 av = *(const float4*)&A[(size_t)(m0 + am) * K1 + k0 + ak];
        const float4 bv = *(const float4*)&B[(size_t)(k0 + bk) * N1 + n0 + bn];
        __syncthreads();
        As[ak + 0][am] = av.x; As[ak + 1][am] = av.y; As[ak + 2][am] = av.z; As[ak + 3][am] = av.w;
        *(float4*)&Bs[bk][bn] = bv;
        __syncthreads();
#pragma unroll
        for (int kk = 0; kk < 16; ++kk) {
            const float4 a = *(const float4*)&As[kk][ty << 2];
            const float4 b = *(const float4*)&Bs[kk][tx << 2];
            const float ar[4] = {a.x, a.y, a.z, a.w};
            const float br[4] = {b.x, b.y, b.z, b.w};
#pragma unroll
            for (int i = 0; i < 4; ++i)
#pragma unroll
                for (int j = 0; j < 4; ++j) acc[i][j] = fmaf(ar[i], br[j], acc[i][j]);
        }
    }
    const float4 bsv = *(const float4*)&bias[n0 + (tx << 2)];
    const float bb[4] = {bsv.x, bsv.y, bsv.z, bsv.w};
#pragma unroll
    for (int i = 0; i < 4; ++i) {
        const int m = m0 + (ty << 2) + i;
        float4 o;
        o.x = fmaxf(acc[i][0] + bb[0], 0.f);
        o.y = fmaxf(acc[i][1] + bb[1], 0.f);
        o.z = fmaxf(acc[i][2] + bb[2], 0.f);
        o.w = fmaxf(acc[i][3] + bb[3], 0.f);
        *(float4*)&C[(size_t)m * N1 + n0 + (tx << 2)] = o;
    }
}

// ---------------------------------------------------------------------------
// GEMM 2: gi0 = x_t @ Wih0^T + bih0  (unchanged)
// ---------------------------------------------------------------------------
__global__ __launch_bounds__(256) void gemm_gi0(const float* __restrict__ xv,
                                                const float* __restrict__ Wih0,
                                                const float* __restrict__ bih0,
                                                float* __restrict__ C) {
    __shared__ float As[16][68];
    __shared__ float Bs[16][68];
    const int tid = threadIdx.x;
    const int m0 = blockIdx.x * 64;
    const int n0 = blockIdx.y * 64;
    const int am = tid >> 2, ak = (tid & 3) << 2;
    const int bn_ = tid >> 2, bkq = (tid & 3) << 2;
    const int ty = tid >> 4, tx = tid & 15;
    const int r = m0 + am;
    const int t = r / 30;
    const int j = r - t * 30;
    const float* rowTrk = xv + ((size_t)(t * 31 + 1 + j) << 9);
    const float* rowImg = xv + ((size_t)(t * 31) << 9);
    float acc[4][4] = {};
    for (int k0 = 0; k0 < K2; k0 += 16) {
        const int kg = k0 + ak;
        const float4 av = (kg < 512) ? *(const float4*)&rowTrk[kg]
                                     : *(const float4*)&rowImg[kg - 512];
        const float4 wv = *(const float4*)&Wih0[(size_t)(n0 + bn_) * K2 + k0 + bkq];
        __syncthreads();
        As[ak + 0][am] = av.x; As[ak + 1][am] = av.y; As[ak + 2][am] = av.z; As[ak + 3][am] = av.w;
        Bs[bkq + 0][bn_] = wv.x; Bs[bkq + 1][bn_] = wv.y; Bs[bkq + 2][bn_] = wv.z; Bs[bkq + 3][bn_] = wv.w;
        __syncthreads();
#pragma unroll
        for (int kk = 0; kk < 16; ++kk) {
            const float4 a = *(const float4*)&As[kk][ty << 2];
            const float4 b = *(const float4*)&Bs[kk][tx << 2];
            const float ar[4] = {a.x, a.y, a.z, a.w};
            const float br[4] = {b.x, b.y, b.z, b.w};
#pragma unroll
            for (int i = 0; i < 4; ++i)
#pragma unroll
                for (int jq = 0; jq < 4; ++jq) acc[i][jq] = fmaf(ar[i], br[jq], acc[i][jq]);
        }
    }
    const float4 bsv = *(const float4*)&bih0[n0 + (tx << 2)];
    const float bb[4] = {bsv.x, bsv.y, bsv.z, bsv.w};
#pragma unroll
    for (int i = 0; i < 4; ++i) {
        const int m = m0 + (ty << 2) + i;
        float4 o;
        o.x = acc[i][0] + bb[0];
        o.y = acc[i][1] + bb[1];
        o.z = acc[i][2] + bb[2];
        o.w = acc[i][3] + bb[3];
        *(float4*)&C[(size_t)m * N2 + n0 + (tx << 2)] = o;
    }
}

// ---------------------------------------------------------------------------
// gic = cor @ Wihc^T + bihc (unchanged)
// ---------------------------------------------------------------------------
__global__ __launch_bounds__(256) void gic_kernel(const int* __restrict__ y,
                                                  const float* __restrict__ Wihc,
                                                  const float* __restrict__ bihc,
                                                  float* __restrict__ gic) {
    const int idx = blockIdx.x * 256 + threadIdx.x;
    if (idx >= M2 * 96) return;
    const int g = idx % 96;
    const int tj = idx / 96;
    const int* yb = y + (size_t)tj * 6;
    const float c0 = (float)yb[1] * (1.f / 1080.f);
    const float c1 = (float)yb[2] * (1.f / 720.f);
    const float c2 = (float)yb[3] * (1.f / 1080.f);
    const float c3 = (float)yb[4] * (1.f / 720.f);
    gic[idx] = bihc[g] + c0 * Wihc[g * 4 + 0] + c1 * Wihc[g * 4 + 1]
                       + c2 * Wihc[g * 4 + 2] + c3 * Wihc[g * 4 + 3];
}

// W1T[u][c] = W1[c][u]  (one-time)
__global__ void transpose_w1(const float* __restrict__ W1, float* __restrict__ W1T) {
    const int idx = blockIdx.x * 256 + threadIdx.x;
    if (idx >= 544 * 256) return;
    const int c = idx % 544, u = idx / 544;
    W1T[idx] = W1[c * 256 + u];
}

__global__ void init_k(unsigned* bar) {
    for (int i = threadIdx.x; i < 1088; i += 256) bar[i] = 0u;
}

// ---------------------------------------------------------------------------
// Two-level fence-free grid barrier (16 groups x 16 WGs), monotonic epochs.
// ---------------------------------------------------------------------------
__device__ __forceinline__ void gbar(unsigned* bar, unsigned ep, int w) {
    __syncthreads();
    if (threadIdx.x == 0) {
        asm volatile("" ::: "memory");
        const int g = w >> 4;
        unsigned* gcnt  = bar + g * 32;
        unsigned* gflag = bar + 544 + g * 32;
        const unsigned tgt = ep * 16u;
        unsigned prev = __hip_atomic_fetch_add(gcnt, 1u, __ATOMIC_RELAXED, __HIP_MEMORY_SCOPE_AGENT);
        if (prev + 1u == tgt) {
            unsigned prevr = __hip_atomic_fetch_add(bar + 512, 1u, __ATOMIC_RELAXED, __HIP_MEMORY_SCOPE_AGENT);
            if (prevr + 1u == tgt) {
                for (int i = 0; i < 16; ++i)
                    __hip_atomic_store(bar + 544 + i * 32, ep, __ATOMIC_RELAXED, __HIP_MEMORY_SCOPE_AGENT);
            } else {
                while (__hip_atomic_load(gflag, __ATOMIC_RELAXED, __HIP_MEMORY_SCOPE_AGENT) < ep)
                    __builtin_amdgcn_s_sleep(1);
            }
        } else {
            while (__hip_atomic_load(gflag, __ATOMIC_RELAXED, __HIP_MEMORY_SCOPE_AGENT) < ep)
                __builtin_amdgcn_s_sleep(1);
        }
        asm volatile("" ::: "memory");
    }
    __syncthreads();
}

// masked softmax over 30 tracks; executes on one full wave; lane param explicit
__device__ __forceinline__ void softmax30_lane(int lane, float sj, int pres, float* outp) {
    float mv = pres ? sj : -1e30f;
    for (int off = 32; off; off >>= 1) mv = fmaxf(mv, __shfl_xor(mv, off));
    float ev = pres ? __expf(sj - mv) : 0.f;
    float sum = ev;
    for (int off = 32; off; off >>= 1) sum += __shfl_xor(sum, off);
    const float inv = 1.f / fmaxf(sum, 1e-9f);
    if (lane < NBOX) outp[lane] = ev * inv;
}

__device__ __forceinline__ void coord_gemv_elem(const float* chc, const float* Whhc, int e, float* cz) {
    const int j = e >> 5, c = e & 31;
    const float* hr = chc + j * 32;
#pragma unroll
    for (int m2 = 0; m2 < 3; ++m2) {
        const float* wr = Whhc + (size_t)(c + 32 * m2) * 32;
        float a = 0.f;
#pragma unroll
        for (int c2 = 0; c2 < 32; c2 += 4) a += dot4(ld4(hr + c2), ld4(wr + c2));
        cz[m2] = a;
    }
}

__device__ __forceinline__ void coord_comb_elem(float* chc, const float* gp, const float* bhhc,
                                                const float* csca, float* hcout, int e, const float* cz) {
    const int j = e >> 5, c = e & 31;
    const float s = csca[j];
    const float r = sigf(gp[j*96 + c]      + s*cz[0] + bhhc[c]);
    const float z = sigf(gp[j*96 + 32 + c] + s*cz[1] + bhhc[32+c]);
    const float n = thf (gp[j*96 + 64 + c] + r*(s*cz[2] + bhhc[64+c]));
    const float hn = (1.f - z)*n + z*(s*chc[e]);
    chc[e] = hn;
    stg_c(hcout + e, hn);
}

struct PArgs {
    const float *gi0, *gic;
    const float *Whh0, *Wih1, *Whh1, *Whhc;
    const float *bhh0, *bih1, *bhh1, *bhhc;
    const float *W1T, *b1, *W2, *b2, *wa, *wac;
    const int *y;
    float *h0g, *h1g, *hcg, *partials, *lossbuf, *out;
    unsigned *bar;
};

// ---------------------------------------------------------------------------
// Fused persistent scan, ONE barrier/step. Scores fused into staging
// (register-side, no LDS-conflict loop). Classifier at v=t-1 from LDS Hs1.
// Coord GRU computes hc(t) at phase t (one phase earlier than R3) so the
// classifier's hc(t-1) is published-before-read across a barrier.
// ---------------------------------------------------------------------------
__global__ __launch_bounds__(256, 1) void persist(PArgs A) {
    extern __shared__ float smem[];
    float* Hs0  = smem;             // [30][516]
    float* Hs1  = smem + 15480;     // [30][516]
    float* Wp   = smem + 30960;     // [12][516] (coord overlay: chc 0..960, cscr @960, csca @992)
    float* gi_s = smem + 37152;     // [30][6]
    float* Z0s  = smem + 37332;     // [30][6]  (alias s0W)
    float* Z1s  = smem + 37512;     // [30][6]  (alias s1W)
    float* sm0  = smem + 37692;
    float* sm1  = smem + 37724;
    float* redF = smem + 37756;     // [72]
    float* hcs  = smem + 37828;     // [960]
    float* s0W = Z0s;               // [30][4] score partials, aliased (read in S2, clobbered in S3)
    float* s1W = Z1s;

    const int w = blockIdx.x;
    const int tid = threadIdx.x;
    const bool isCoord = (w == NWG - 1);
    unsigned ep = 0;
    float lossSum = 0.f;

    // ---- one-time weight preload into LDS (stride 516: bank-spread) ----
    if (!isCoord) {
#pragma unroll
        for (int i = 0; i < 6; ++i) {
            const int fid = tid + 256 * i;            // 0..1535
            const int slot = fid >> 7;                // 0..11
            const int k4 = (fid & 127) << 2;          // 0..508
            const int sl = slot % 6;
            const int col = (sl % 3) * 512 + 2 * w + ((sl >= 3) ? 1 : 0);
            const float* mat = (slot < 6) ? A.Whh0 : A.Wih1;
            *(float4*)&Wp[slot * 516 + k4] = ld4(mat + (size_t)col * 512 + k4);
        }
    } else {
        for (int i = tid; i < 1024; i += 256) Wp[i] = 0.f;  // chc(960)+cscr(32)+csca(32)
    }
    if (tid < 180) Z1s[tid] = 0.f;                    // t=0 combine reads with s=0

    // ---- hoisted per-thread constants ----
    const int cjX = tid >> 1, ciX = tid & 1, cX = 2 * w + ciX;   // combine map (tid<60)
    float b0r=0,b0z=0,b0n=0,b1r=0,b1z=0,b1n=0;
    if (tid < 60) {
        b0r = A.bhh0[cX]; b0z = A.bhh0[512+cX]; b0n = A.bhh0[1024+cX];
        b1r = A.bhh1[cX]; b1z = A.bhh1[512+cX]; b1n = A.bhh1[1024+cX];
    }
    float biA = 0.f, biB = 0.f;
    {
        const int q = tid & 7;
        if (tid < 240 && q >= 3 && q < 6) {
            const int slA = 2 * (q - 3), slB = slA + 1;
            biA = A.bih1[(slA % 3) * 512 + 2 * w + ((slA >= 3) ? 1 : 0)];
            biB = A.bih1[(slB % 3) * 512 + 2 * w + ((slB >= 3) ? 1 : 0)];
        }
    }
    float clb=0,c20=0,c21=0, clb2=0,c202=0,c212=0;
    if (!isCoord) { clb = A.b1[w]; c20 = A.W2[2*w]; c21 = A.W2[2*w+1]; }
    if (w == 254) { clb2 = A.b1[255]; c202 = A.W2[510]; c212 = A.W2[511]; }
    const float waX = A.wa[2 * tid], waY = A.wa[2 * tid + 1];

    float cz0[3]={0,0,0}, cz1[3]={0,0,0}, cz2[3]={0,0,0}, cz3[3]={0,0,0};

    // ---- INIT: h0_n(0) (zero state -> s=0 path), publish to h0g slot 0 ----
    if (tid < 60) {
        const float* gp = A.gi0 + cjX * 1536;
        const float r = sigf(gp[cX] + b0r);
        const float z = sigf(gp[512 + cX] + b0z);
        const float n = thf(gp[1024 + cX] + r * b0n);
        stg_c(A.h0g + cjX * 512 + cX, (1.f - z) * n);
    }
    gbar(A.bar, ++ep, w);

    for (int t = 0; t < TT + 2; ++t) {
        // ================= S0: staging with fused scores =================
        if (t <= 511) {
            const float* src = A.h0g + (t & 1) * 15360 + 2 * tid;
#pragma unroll
            for (int i = 0; i < 30; ++i) {
                const float2 v = ldg_c2(src + i * 512);
                *(float2*)&Hs0[i * 516 + 2 * tid] = v;
                float p = thf(v.x) * waX + thf(v.y) * waY;
                p += __shfl_down(p, 32); p += __shfl_down(p, 16); p += __shfl_down(p, 8);
                p += __shfl_down(p, 4);  p += __shfl_down(p, 2);  p += __shfl_down(p, 1);
                if ((tid & 63) == 0) s0W[i * 4 + (tid >> 6)] = p;
            }
        }
        if (t == 0) {
            const float2 zz = make_float2(0.f, 0.f);
#pragma unroll
            for (int i = 0; i < 30; ++i) *(float2*)&Hs1[i * 516 + 2 * tid] = zz;
        } else if (t <= 511) {
            const float* src = A.h1g + ((t + 2) % 3) * 15360 + 2 * tid;
#pragma unroll
            for (int i = 0; i < 30; ++i) {
                const float2 v = ldg_c2(src + i * 512);
                *(float2*)&Hs1[i * 516 + 2 * tid] = v;
                float p = thf(v.x) * waX + thf(v.y) * waY;
                p += __shfl_down(p, 32); p += __shfl_down(p, 16); p += __shfl_down(p, 8);
                p += __shfl_down(p, 4);  p += __shfl_down(p, 2);  p += __shfl_down(p, 1);
                if ((tid & 63) == 0) s1W[i * 4 + (tid >> 6)] = p;
            }
        } else if (t == 512) {     // classifier still needs h1(511); no scores
            const float* src = A.h1g + ((t + 2) % 3) * 15360 + 2 * tid;
#pragma unroll
            for (int i = 0; i < 30; ++i) {
                const float2 v = ldg_c2(src + i * 512);
                *(float2*)&Hs1[i * 516 + 2 * tid] = v;
            }
        }
        // stage hc(t-1) for classifier
        if (!isCoord && t >= 1 && t <= 512) {
            const float* hsrc = A.hcg + ((t - 1) & 1) * 960;
            for (int fi = tid; fi < 480; fi += 256)
                *(float2*)&hcs[fi << 1] = ldg_c2(hsrc + (fi << 1));
        }
        // prefetch gi0(t+1) (read-only, normal cached loads)
        float g_r = 0.f, g_z = 0.f, g_n = 0.f;
        if (tid < 60 && t <= 510) {
            const float* gp = A.gi0 + (size_t)(t + 1) * 46080 + cjX * 1536;
            g_r = gp[cX]; g_z = gp[512 + cX]; g_n = gp[1024 + cX];
        }
        __syncthreads();   // Hs + score partials ready

        // ================= S2: softmaxes (wave-parallel) =================
        {
            const int wv = tid >> 6;
            if (wv == 0) {
                if (t <= 511) {
                    float sj = 0.f; int pres = 0;
                    if (tid < NBOX) {
                        const float4 s4 = ld4(&s0W[tid * 4]);
                        sj = s4.x + s4.y + s4.z + s4.w;
                        pres = (A.y[(size_t)t * 180 + tid * 6] != 0);
                    }
                    softmax30_lane(tid, sj, pres, sm0);
                }
            } else if (wv == 1) {
                const int lane = tid - 64;
                if (t >= 1 && t <= 511) {
                    float sj = 0.f; int pres = 0;
                    if (lane < NBOX) {
                        const float4 s4 = ld4(&s1W[lane * 4]);
                        sj = s4.x + s4.y + s4.z + s4.w;
                        pres = (A.y[(size_t)(t - 1) * 180 + lane * 6] != 0);
                    }
                    softmax30_lane(lane, sj, pres, sm1);
                } else if (t == 0) {
                    if (lane < NBOX) sm1[lane] = 0.f;
                }
            } else if (wv == 2 && isCoord && t <= 511) {
                const int lane = tid - 128;
                float* cscr = Wp + 960;
                float* csca = Wp + 992;
                if (t == 0) { if (lane < NBOX) csca[lane] = 0.f; }
                else {
                    float sj = 0.f; int pres = 0;
                    if (lane < NBOX) { sj = cscr[lane]; pres = (A.y[(size_t)(t - 1) * 180 + lane * 6] != 0); }
                    softmax30_lane(lane, sj, pres, csca);
                }
            }
        }
        __syncthreads();   // sm0/sm1/csca ready

        // ================= S3: GEMVs + coord combine =================
        if (t <= 511 && tid < 240) {
            const int j = tid >> 3, q = tid & 7;
            if (q < 6) {
                const float* hrow = &Hs0[j * 516];
                const int saA = (q < 3) ? (2 * q) : (6 + 2 * (q - 3));
                float a0 = 0.f, a1 = 0.f;
                if (!isCoord) {
                    const float* wA = &Wp[saA * 516];
                    const float* wB = &Wp[(saA + 1) * 516];
#pragma unroll 4
                    for (int k = 0; k < 512; k += 4) {
                        const float4 h4 = ld4(hrow + k);
                        a0 += dot4(h4, ld4(wA + k));
                        a1 += dot4(h4, ld4(wB + k));
                    }
                } else {
                    const int slA = saA % 6, slB = slA + 1;
                    const float* mat = (saA < 6) ? A.Whh0 : A.Wih1;
                    const float* wA = mat + (size_t)((slA % 3) * 512 + 2 * w + ((slA >= 3) ? 1 : 0)) * 512;
                    const float* wB = mat + (size_t)((slB % 3) * 512 + 2 * w + ((slB >= 3) ? 1 : 0)) * 512;
#pragma unroll 4
                    for (int k = 0; k < 512; k += 4) {
                        const float4 h4 = ld4(hrow + k);
                        a0 += dot4(h4, ld4(wA + k));
                        a1 += dot4(h4, ld4(wB + k));
                    }
                }
                if (q < 3) { Z0s[j * 6 + 2 * q] = a0; Z0s[j * 6 + 2 * q + 1] = a1; }
                else { const int g = 2 * (q - 3); gi_s[j * 6 + g] = a0 + biA; gi_s[j * 6 + g + 1] = a1 + biB; }
            }
        }
        if (t >= 1 && t <= 511 && tid < 240) {
            const int j = tid >> 3, q = tid & 7;
            if (q < 3) {   // Whh1 from global (read-only, L1/L2 cached)
                const float* hrow = &Hs1[j * 516];
                const int slA = 2 * q, slB = slA + 1;
                const float* wA = A.Whh1 + (size_t)((slA % 3) * 512 + 2 * w + ((slA >= 3) ? 1 : 0)) * 512;
                const float* wB = A.Whh1 + (size_t)((slB % 3) * 512 + 2 * w + ((slB >= 3) ? 1 : 0)) * 512;
                float a0 = 0.f, a1 = 0.f;
#pragma unroll 4
                for (int k = 0; k < 512; k += 4) {
                    const float4 h4 = ld4(hrow + k);
                    a0 += dot4(h4, ld4(wA + k));
                    a1 += dot4(h4, ld4(wB + k));
                }
                Z1s[j * 6 + 2 * q] = a0; Z1s[j * 6 + 2 * q + 1] = a1;
            }
        }
        if (isCoord && t <= 511) {   // coord combine: hc(t), publish
            float* chc = Wp;
            float* csca = Wp + 992;
            const float* gp = A.gic + (size_t)t * 2880;
            float* hcout = A.hcg + (t & 1) * 960;
            if (tid < 960)       coord_comb_elem(chc, gp, A.bhhc, csca, hcout, tid, cz0);
            if (tid + 256 < 960) coord_comb_elem(chc, gp, A.bhhc, csca, hcout, tid + 256, cz1);
            if (tid + 512 < 960) coord_comb_elem(chc, gp, A.bhhc, csca, hcout, tid + 512, cz2);
            if (tid + 768 < 960) coord_comb_elem(chc, gp, A.bhhc, csca, hcout, tid + 768, cz3);
        }
        __syncthreads();   // Z0s/gi_s/Z1s/chc ready

        // ================= S5: combines + coord GEMV + classifier + finalize =================
        if (tid < 60 && t <= 511) {          // h1-combine(t)
            const float s = sm1[cjX];
            const float r = sigf(gi_s[cjX*6 + ciX*3 + 0] + s * Z1s[cjX*6 + ciX*3 + 0] + b1r);
            const float z = sigf(gi_s[cjX*6 + ciX*3 + 1] + s * Z1s[cjX*6 + ciX*3 + 1] + b1z);
            const float n = thf (gi_s[cjX*6 + ciX*3 + 2] + r * (s * Z1s[cjX*6 + ciX*3 + 2] + b1n));
            const float h1p = Hs1[cjX * 516 + cX];
            stg_c(A.h1g + (t % 3) * 15360 + cjX * 512 + cX, (1.f - z) * n + z * (s * h1p));
        }
        if (tid < 60 && t <= 510) {          // h0-combine(t+1)
            const float s = sm0[cjX];
            const float r = sigf(g_r + s * Z0s[cjX*6 + ciX*3 + 0] + b0r);
            const float z = sigf(g_z + s * Z0s[cjX*6 + ciX*3 + 1] + b0z);
            const float n = thf (g_n + r * (s * Z0s[cjX*6 + ciX*3 + 2] + b0n));
            const float h0p = Hs0[cjX * 516 + cX];
            stg_c(A.h0g + ((t + 1) & 1) * 15360 + cjX * 512 + cX, (1.f - z) * n + z * (s * h0p));
        }
        if (isCoord && t <= 511) {           // coord Zc GEMV + raw scores for next phase
            float* chc = Wp;
            float* cscr = Wp + 960;
            if (tid < 960)       coord_gemv_elem(chc, A.Whhc, tid, cz0);
            if (tid + 256 < 960) coord_gemv_elem(chc, A.Whhc, tid + 256, cz1);
            if (tid + 512 < 960) coord_gemv_elem(chc, A.Whhc, tid + 512, cz2);
            if (tid + 768 < 960) coord_gemv_elem(chc, A.Whhc, tid + 768, cz3);
            if (tid < 240) {
                const int j = tid >> 3, seg = tid & 7;
                float p = 0.f;
#pragma unroll
                for (int c2 = seg * 4; c2 < seg * 4 + 4; ++c2) p += thf(chc[j * 32 + c2]) * A.wac[c2];
                p += __shfl_down(p, 4, 8); p += __shfl_down(p, 2, 8); p += __shfl_down(p, 1, 8);
                if (seg == 0) cscr[j] = p;
            }
        }
        if (!isCoord && t >= 1 && t <= 512 && tid < 240) {  // classifier unit w @ v=t-1, LDS operands
            const int j = tid >> 3, q = tid & 7;
            const float* hrow = &Hs1[j * 516];
            {
                const float* w1r = A.W1T + (size_t)w * 544;
                float acc = 0.f;
#pragma unroll
                for (int i = 0; i < 16; ++i) {
                    const int k = q * 4 + 32 * i;
                    acc += dot4(ld4(hrow + k), ld4(w1r + k));
                }
                if (q == 7) {
                    const float* hcr = &hcs[j * 32];
                    const float* w1h = w1r + 512;
#pragma unroll
                    for (int c2 = 0; c2 < 32; c2 += 4) acc += dot4(ld4(hcr + c2), ld4(w1h + c2));
                }
                acc += __shfl_down(acc, 4, 8); acc += __shfl_down(acc, 2, 8); acc += __shfl_down(acc, 1, 8);
                if (q == 0) {
                    const float uu = fmaxf(clb + acc, 0.f);
                    stg_c2(A.partials + (t & 1) * 16384 + w * 64 + j * 2, uu * c20, uu * c21);
                }
            }
            if (w == 254) {  // also unit 255
                const float* w1r = A.W1T + (size_t)255 * 544;
                float acc = 0.f;
#pragma unroll
                for (int i = 0; i < 16; ++i) {
                    const int k = q * 4 + 32 * i;
                    acc += dot4(ld4(hrow + k), ld4(w1r + k));
                }
                if (q == 7) {
                    const float* hcr = &hcs[j * 32];
                    const float* w1h = w1r + 512;
#pragma unroll
                    for (int c2 = 0; c2 < 32; c2 += 4) acc += dot4(ld4(hcr + c2), ld4(w1h + c2));
                }
                acc += __shfl_down(acc, 4, 8); acc += __shfl_down(acc, 2, 8); acc += __shfl_down(acc, 1, 8);
                if (q == 0) {
                    const float uu = fmaxf(clb2 + acc, 0.f);
                    stg_c2(A.partials + (t & 1) * 16384 + 255 * 64 + j * 2, uu * c202, uu * c212);
                }
            }
        }
        if (w < 30 && t >= 2) {              // finalize f=t-2 (track j = w): partial sums
            const float* pp = A.partials + ((t - 1) & 1) * 16384;
            const float2 v2 = ldg_c2(pp + tid * 64 + w * 2);
            float q0 = v2.x, q1 = v2.y;
            for (int off = 32; off; off >>= 1) { q0 += __shfl_down(q0, off); q1 += __shfl_down(q1, off); }
            if ((tid & 63) == 0) { redF[60 + (tid >> 6) * 2] = q0; redF[61 + (tid >> 6) * 2] = q1; }
        }
        __syncthreads();
        if (w < 30 && t >= 2 && tid == 0) {
            const int f = t - 2;
            float o0 = A.b2[0] + redF[60] + redF[62] + redF[64] + redF[66];
            float o1 = A.b2[1] + redF[61] + redF[63] + redF[65] + redF[67];
            const int* yb = A.y + (size_t)f * 180 + w * 6;
            const float pm = (yb[0] != 0) ? 1.f : 0.f;
            const float m = fmaxf(o0, o1);
            const float lse = m + __logf(__expf(o0 - m) + __expf(o1 - m));
            const float lt = (yb[5] == 0) ? o0 : o1;
            lossSum += pm * (lse - lt);
            A.out[1 + (size_t)f * 60 + w * 2]     = o0 * pm;
            A.out[1 + (size_t)f * 60 + w * 2 + 1] = o1 * pm;
        }
        gbar(A.bar, ++ep, w);
    }

    // ---- total loss ----
    if (w < 30 && tid == 0) stg_c(A.lossbuf + w, lossSum);
    gbar(A.bar, ++ep, w);
    if (w == 0 && tid == 0) {
        float s = 0.f;
        for (int j = 0; j < NBOX; ++j) s += ldg_c(A.lossbuf + j);
        A.out[0] = s;
    }
}

// ---------------------------------------------------------------------------
extern "C" void kernel_launch(void* const* d_in, const int* in_sizes, int n_in,
                              void* d_out, int out_size, void* d_ws, size_t ws_size,
                              hipStream_t stream) {
    (void)in_sizes; (void)n_in; (void)out_size; (void)ws_size;
    const int*   y     = (const int*)d_in[1];
    const float* flow  = (const float*)d_in[2];
    const float* W_phi = (const float*)d_in[3];
    const float* b_phi = (const float*)d_in[4];
    const float* Wih0  = (const float*)d_in[5];
    const float* Whh0  = (const float*)d_in[6];
    const float* bih0  = (const float*)d_in[7];
    const float* bhh0  = (const float*)d_in[8];
    const float* Wih1  = (const float*)d_in[9];
    const float* Whh1  = (const float*)d_in[10];
    const float* bih1  = (const float*)d_in[11];
    const float* bhh1  = (const float*)d_in[12];
    const float* Wihc  = (const float*)d_in[13];
    const float* Whhc  = (const float*)d_in[14];
    const float* bihc  = (const float*)d_in[15];
    const float* bhhc  = (const float*)d_in[16];
    const float* W1    = (const float*)d_in[17];
    const float* b1    = (const float*)d_in[18];
    const float* W2    = (const float*)d_in[19];
    const float* b2    = (const float*)d_in[20];
    const float* wa    = (const float*)d_in[21];
    const float* wac   = (const float*)d_in[22];
    float* out = (float*)d_out;

    float* ws = (float*)d_ws;
    float* xv   = ws;  ws += (size_t)M1 * N1;
    float* gi0  = ws;  ws += (size_t)M2 * N2;
    float* gic  = ws;  ws += (size_t)M2 * 96;
    float* W1T  = ws;  ws += 544 * 256;
    float* h0g  = ws;  ws += 2 * NBOX * 512;
    float* h1g  = ws;  ws += 3 * NBOX * 512;
    float* hcg  = ws;  ws += 2 * NBOX * 32;
    float* partials = ws; ws += 2 * 256 * 64;
    float* lossbuf  = ws; ws += 32;
    unsigned* barmem = (unsigned*)ws; ws += 1088;

    (void)hipFuncSetAttribute((const void*)persist,
                              hipFuncAttributeMaxDynamicSharedMemorySize, DYN_BYTES);

    hipLaunchKernelGGL(init_k, dim3(1), dim3(256), 0, stream, barmem);
    hipLaunchKernelGGL(gemm_phi, dim3(M1 / 64, N1 / 64), dim3(256), 0, stream, flow, W_phi, b_phi, xv);
    hipLaunchKernelGGL(gemm_gi0, dim3(M2 / 64, N2 / 64), dim3(256), 0, stream, xv, Wih0, bih0, gi0);
    hipLaunchKernelGGL(gic_kernel, dim3((M2 * 96 + 255) / 256), dim3(256), 0, stream, y, Wihc, bihc, gic);
    hipLaunchKernelGGL(transpose_w1, dim3((544 * 256 + 255) / 256), dim3(256), 0, stream, W1, W1T);

    PArgs A;
    A.gi0 = gi0; A.gic = gic;
    A.Whh0 = Whh0; A.Wih1 = Wih1; A.Whh1 = Whh1; A.Whhc = Whhc;
    A.bhh0 = bhh0; A.bih1 = bih1; A.bhh1 = bhh1; A.bhhc = bhhc;
    A.W1T = W1T; A.b1 = b1; A.W2 = W2; A.b2 = b2; A.wa = wa; A.wac = wac;
    A.y = y;
    A.h0g = h0g; A.h1g = h1g; A.hcg = hcg;
    A.partials = partials; A.lossbuf = lossbuf; A.out = out;
    A.bar = barmem;
    hipLaunchKernelGGL(persist, dim3(NWG), dim3(256), DYN_BYTES, stream, A);
}